// Round 7
// baseline (97.456 us; speedup 1.0000x reference)
//
#include <hip/hip_runtime.h>
#include <hip/hip_bf16.h>

#define NB   64
#define NREG 4
#define ND   768
#define NH   37
#define NW   37
#define NC   5                      // 1 + NREG cues
#define NP   (NH * NW)              // 1369
#define BPB  12                     // blocks per batch -> 768 blocks = 3/CU exactly
#define PPB  ((NP + BPB - 1) / BPB) // 115 patches per block
#define NWAVE 4
#define DEPTH 5                     // register pipeline depth (prefetch distance 4)

// Map float -> unsigned int preserving order (total order, -inf .. +inf)
__device__ __forceinline__ unsigned int ord_of(float f) {
    unsigned int u = __float_as_uint(f);
    return (u & 0x80000000u) ? ~u : (u | 0x80000000u);
}

// DPP-based wave64 sum: 6 full-rate VALU steps, no LDS ops, no lgkm waits.
// Result is the full 64-lane sum in LANE 63 (other lanes hold partials).
template <int CTRL>
__device__ __forceinline__ float dpp_add_step(float x) {
    int y = __builtin_amdgcn_update_dpp(0, __float_as_int(x), CTRL, 0xf, 0xf, true);
    return x + __int_as_float(y);
}
__device__ __forceinline__ float wave_sum_lane63(float x) {
    x = dpp_add_step<0x111>(x);  // row_shr:1
    x = dpp_add_step<0x112>(x);  // row_shr:2
    x = dpp_add_step<0x114>(x);  // row_shr:4
    x = dpp_add_step<0x118>(x);  // row_shr:8
    x = dpp_add_step<0x142>(x);  // row_bcast:15
    x = dpp_add_step<0x143>(x);  // row_bcast:31
    return x;                    // lane 63 = total
}

__global__ __launch_bounds__(256, 3) void sim_argmax_kernel(
    const float* __restrict__ cls_tok,
    const float* __restrict__ regs,
    const float* __restrict__ patches,
    unsigned long long* __restrict__ pkeys)
{
    const int b    = blockIdx.x / BPB;
    const int pb   = blockIdx.x % BPB;
    const int wave = threadIdx.x >> 6;
    const int lane = threadIdx.x & 63;

    // Preload this lane's slice of all 5 cues into registers (15 float4).
    float4 cue[NC][3];
    #pragma unroll
    for (int c = 0; c < NC; ++c) {
        const float* cb = (c == 0) ? (cls_tok + (size_t)b * ND)
                                   : (regs + ((size_t)b * NREG + (c - 1)) * ND);
        #pragma unroll
        for (int k = 0; k < 3; ++k)
            cue[c][k] = *reinterpret_cast<const float4*>(cb + k * 256 + lane * 4);
    }

    float best[NC];
    int   bidx[NC];
    #pragma unroll
    for (int c = 0; c < NC; ++c) { best[c] = -3.4e38f; bidx[c] = 0; }

    const int pstart = pb * PPB;
    const int p1     = min(NP, pstart + PPB);
    const size_t bb  = (size_t)b * NP;
    int p = pstart + wave;   // wave-uniform stepping by NWAVE

#define LOAD_SLOT(Sa, Sb, Sc, pp)                                              \
    {                                                                          \
        const float* g_ = patches + (bb + (pp)) * ND + lane * 4;               \
        Sa = *reinterpret_cast<const float4*>(g_);                             \
        Sb = *reinterpret_cast<const float4*>(g_ + 256);                       \
        Sc = *reinterpret_cast<const float4*>(g_ + 512);                       \
    }

    float4 S0a, S0b, S0c, S1a, S1b, S1c, S2a, S2b, S2c,
           S3a, S3b, S3c, S4a, S4b, S4c;
    const float4 z = make_float4(0.f, 0.f, 0.f, 0.f);
    S0a=S0b=S0c=S1a=S1b=S1c=S2a=S2b=S2c=S3a=S3b=S3c=S4a=S4b=S4c=z;

    // Prologue: fill all DEPTH slots (prefetch distance = DEPTH-1 iterations).
    if (p + 0*NWAVE < p1) LOAD_SLOT(S0a, S0b, S0c, p + 0*NWAVE);
    if (p + 1*NWAVE < p1) LOAD_SLOT(S1a, S1b, S1c, p + 1*NWAVE);
    if (p + 2*NWAVE < p1) LOAD_SLOT(S2a, S2b, S2c, p + 2*NWAVE);
    if (p + 3*NWAVE < p1) LOAD_SLOT(S3a, S3b, S3c, p + 3*NWAVE);
    if (p + 4*NWAVE < p1) LOAD_SLOT(S4a, S4b, S4c, p + 4*NWAVE);

#define BODY(Sa, Sb, Sc)                                                       \
    {                                                                          \
        float s_[NC];                                                          \
        _Pragma("unroll")                                                      \
        for (int c = 0; c < NC; ++c) {                                         \
            s_[c] = Sa.x * cue[c][0].x + Sa.y * cue[c][0].y                    \
                  + Sa.z * cue[c][0].z + Sa.w * cue[c][0].w                    \
                  + Sb.x * cue[c][1].x + Sb.y * cue[c][1].y                    \
                  + Sb.z * cue[c][1].z + Sb.w * cue[c][1].w                    \
                  + Sc.x * cue[c][2].x + Sc.y * cue[c][2].y                    \
                  + Sc.z * cue[c][2].z + Sc.w * cue[c][2].w;                   \
        }                                                                      \
        const int pf_ = p + DEPTH * NWAVE;                                     \
        if (pf_ < p1) LOAD_SLOT(Sa, Sb, Sc, pf_);                              \
        _Pragma("unroll")                                                      \
        for (int c = 0; c < NC; ++c) {                                         \
            const float t_ = wave_sum_lane63(s_[c]);                           \
            if (t_ > best[c]) { best[c] = t_; bidx[c] = p; }                   \
        }                                                                      \
        p += NWAVE;                                                            \
        if (p >= p1) goto done;                                                \
    }

    if (p < p1) {
        while (true) {
            BODY(S0a, S0b, S0c)
            BODY(S1a, S1b, S1c)
            BODY(S2a, S2b, S2c)
            BODY(S3a, S3b, S3c)
            BODY(S4a, S4b, S4c)
        }
    }
done: ;
#undef BODY
#undef LOAD_SLOT

    // Combine the 4 waves' bests in LDS, then one plain store per cue.
    __shared__ unsigned long long lk[NWAVE][NC];
    if (lane == 63) {  // DPP sum lives in lane 63
        #pragma unroll
        for (int c = 0; c < NC; ++c) {
            lk[wave][c] =
                ((unsigned long long)ord_of(best[c]) << 32) |
                (unsigned long long)(unsigned)(NP - 1 - bidx[c]);  // low idx wins ties
        }
    }
    __syncthreads();
    if (threadIdx.x < NC) {
        unsigned long long k = lk[0][threadIdx.x];
        k = max(k, lk[1][threadIdx.x]);
        k = max(k, lk[2][threadIdx.x]);
        k = max(k, lk[3][threadIdx.x]);
        pkeys[(b * NC + threadIdx.x) * BPB + pb] = k;
    }
}

// One block per (b, cue): reduce partial keys, clipped-window mean,
// normalize cue & roi tokens.
__global__ __launch_bounds__(256) void roi_norm_kernel(
    const float* __restrict__ cls_tok,
    const float* __restrict__ regs,
    const float* __restrict__ patches,
    const unsigned long long* __restrict__ pkeys,
    const int* __restrict__ roi_side_p,
    float* __restrict__ out)
{
    const int b   = blockIdx.x / NC;
    const int c   = blockIdx.x % NC;
    const int tid = threadIdx.x;
    const int wave = tid >> 6, lane = tid & 63;
    const int r = roi_side_p[0] >> 1;

    // All threads redundantly reduce the BPB partial keys (uniform loads).
    const unsigned long long* pk = pkeys + (b * NC + c) * BPB;
    unsigned long long key = pk[0];
    #pragma unroll
    for (int i = 1; i < BPB; ++i) key = max(key, pk[i]);

    const int idx = NP - 1 - (int)(key & 0xFFFFFFFFu);
    const int hh = idx / NW, ww = idx % NW;
    const int h0 = max(0, hh - r), h1 = min(NH - 1, hh + r);
    const int w0 = max(0, ww - r), w1 = min(NW - 1, ww + r);
    const float inv_cnt = 1.0f / (float)((h1 - h0 + 1) * (w1 - w0 + 1));

    float a0 = 0.f, a1 = 0.f, a2 = 0.f;
    for (int h = h0; h <= h1; ++h) {
        for (int w = w0; w <= w1; ++w) {
            const float* p = patches + ((size_t)b * NP + h * NW + w) * ND;
            a0 += p[tid];
            a1 += p[tid + 256];
            a2 += p[tid + 512];
        }
    }
    a0 *= inv_cnt; a1 *= inv_cnt; a2 *= inv_cnt;

    const float* cb = (c == 0) ? (cls_tok + (size_t)b * ND)
                               : (regs + ((size_t)b * NREG + (c - 1)) * ND);
    const float v0 = cb[tid], v1 = cb[tid + 256], v2 = cb[tid + 512];

    // Block-reduce two sums of squares (cue, roi).
    float sx = v0 * v0 + v1 * v1 + v2 * v2;
    float sy = a0 * a0 + a1 * a1 + a2 * a2;
    #pragma unroll
    for (int off = 32; off > 0; off >>= 1) {
        sx += __shfl_xor(sx, off, 64);
        sy += __shfl_xor(sy, off, 64);
    }
    __shared__ float red_x[4], red_y[4];
    if (lane == 0) { red_x[wave] = sx; red_y[wave] = sy; }
    __syncthreads();
    const float tot_x = red_x[0] + red_x[1] + red_x[2] + red_x[3];
    const float tot_y = red_y[0] + red_y[1] + red_y[2] + red_y[3];
    const float inv_nc = 1.0f / fmaxf(sqrtf(tot_x), 1e-12f);
    const float inv_nr = 1.0f / fmaxf(sqrtf(tot_y), 1e-12f);

    float* oc = out + ((size_t)b * 2 * NC + c) * ND;       // cue token
    float* om = out + ((size_t)b * 2 * NC + NC + c) * ND;  // roi token
    oc[tid]       = v0 * inv_nc;
    oc[tid + 256] = v1 * inv_nc;
    oc[tid + 512] = v2 * inv_nc;
    om[tid]       = a0 * inv_nr;
    om[tid + 256] = a1 * inv_nr;
    om[tid + 512] = a2 * inv_nr;
}

extern "C" void kernel_launch(void* const* d_in, const int* in_sizes, int n_in,
                              void* d_out, int out_size, void* d_ws, size_t ws_size,
                              hipStream_t stream) {
    const float* cls_tok = (const float*)d_in[0];
    const float* regs    = (const float*)d_in[1];
    const float* patches = (const float*)d_in[2];
    const int*   roi     = (const int*)d_in[3];
    float* out = (float*)d_out;
    unsigned long long* pkeys = (unsigned long long*)d_ws;

    sim_argmax_kernel<<<NB * BPB, 256, 0, stream>>>(cls_tok, regs, patches, pkeys);
    roi_norm_kernel<<<NB * NC, 256, 0, stream>>>(cls_tok, regs, patches, pkeys, roi, out);
}

// Round 8
// 58.339 us; speedup vs baseline: 1.6705x; 1.6705x over previous
//
#include <hip/hip_runtime.h>
#include <hip/hip_bf16.h>

#define NB   64
#define NREG 4
#define ND   768
#define NH   37
#define NW   37
#define NC   5                      // 1 + NREG cues
#define NP   (NH * NW)              // 1369
#define BPB  16                     // blocks per batch -> 1024 blocks = 4/CU
#define PPB  ((NP + BPB - 1) / BPB) // 86 patches per block
#define NWAVE 4
#define DEPTH 3                     // LDS slots per wave (private triple buffer)

// Map float -> unsigned int preserving order (total order, -inf .. +inf)
__device__ __forceinline__ unsigned int ord_of(float f) {
    unsigned int u = __float_as_uint(f);
    return (u & 0x80000000u) ? ~u : (u | 0x80000000u);
}

// DPP-based wave64 sum: 6 full-rate VALU steps, no LDS ops, no lgkm waits.
// Result is the full 64-lane sum in LANE 63 (other lanes hold partials).
template <int CTRL>
__device__ __forceinline__ float dpp_add_step(float x) {
    int y = __builtin_amdgcn_update_dpp(0, __float_as_int(x), CTRL, 0xf, 0xf, true);
    return x + __int_as_float(y);
}
__device__ __forceinline__ float wave_sum_lane63(float x) {
    x = dpp_add_step<0x111>(x);  // row_shr:1
    x = dpp_add_step<0x112>(x);  // row_shr:2
    x = dpp_add_step<0x114>(x);  // row_shr:4
    x = dpp_add_step<0x118>(x);  // row_shr:8
    x = dpp_add_step<0x142>(x);  // row_bcast:15
    x = dpp_add_step<0x143>(x);  // row_bcast:31
    return x;                    // lane 63 = total
}

// Issue 3x global_load_lds (1 KB each) for one patch into one wave-slot.
__device__ __forceinline__ void stage_patch(const float* __restrict__ gbase,
                                            float* lslot, int lane) {
    const float* g = gbase + lane * 4;
    #pragma unroll
    for (int k = 0; k < 3; ++k) {
        __builtin_amdgcn_global_load_lds(
            (const __attribute__((address_space(1))) void*)(g + k * 256),
            (__attribute__((address_space(3))) void*)(lslot + k * 256),
            16, 0, 0);
    }
}

__global__ __launch_bounds__(256, 4) void sim_argmax_kernel(
    const float* __restrict__ cls_tok,
    const float* __restrict__ regs,
    const float* __restrict__ patches,
    unsigned long long* __restrict__ pkeys)
{
    const int b    = blockIdx.x / BPB;
    const int pb   = blockIdx.x % BPB;
    const int wave = threadIdx.x >> 6;
    const int lane = threadIdx.x & 63;

    // Per-wave private staging buffers: 3 slots x 3 KB. No barriers needed.
    __shared__ float lds[DEPTH][NWAVE][ND];   // 36 KB

    // Preload this lane's slice of all 5 cues into registers (15 float4).
    float4 cue[NC][3];
    #pragma unroll
    for (int c = 0; c < NC; ++c) {
        const float* cb = (c == 0) ? (cls_tok + (size_t)b * ND)
                                   : (regs + ((size_t)b * NREG + (c - 1)) * ND);
        #pragma unroll
        for (int k = 0; k < 3; ++k)
            cue[c][k] = *reinterpret_cast<const float4*>(cb + k * 256 + lane * 4);
    }

    float best[NC];
    int   bidx[NC];
    #pragma unroll
    for (int c = 0; c < NC; ++c) { best[c] = -3.4e38f; bidx[c] = 0; }

    const int pstart = pb * PPB;
    const int p1     = min(NP, pstart + PPB);
    const size_t bb  = (size_t)b * NP;
    const int p0     = pstart + wave;   // wave-uniform

    // Prologue: fill all three slots.
    #pragma unroll
    for (int s = 0; s < DEPTH; ++s) {
        const int pp = p0 + s * NWAVE;
        if (pp < p1) stage_patch(patches + (bb + pp) * ND, &lds[s][wave][0], lane);
    }

    int it = 0;
    for (int pp = p0; pp < p1; pp += NWAVE, ++it) {
        const int s = it % DEPTH;

        // Counted wait: my slot's 3 loads done; other slots' loads in flight.
        // Outstanding-not-mine = 3 * (#future slots already staged).
        const bool n2 = (pp + 2 * NWAVE) < p1;   // wave-uniform
        const bool n1 = (pp + NWAVE) < p1;
        if (n2)      asm volatile("s_waitcnt vmcnt(6)" ::: "memory");
        else if (n1) asm volatile("s_waitcnt vmcnt(3)" ::: "memory");
        else         asm volatile("s_waitcnt vmcnt(0)" ::: "memory");

        const float* l = &lds[s][wave][0] + lane * 4;
        const float4 v0 = *reinterpret_cast<const float4*>(l);
        const float4 v1 = *reinterpret_cast<const float4*>(l + 256);
        const float4 v2 = *reinterpret_cast<const float4*>(l + 512);

        // Ensure the ds_reads complete before re-staging overwrites the slot.
        asm volatile("s_waitcnt lgkmcnt(0)" ::: "memory");

        // Prefetch this slot <- patch pp + 12 (issues while we compute).
        const int pf = pp + DEPTH * NWAVE;
        if (pf < p1) stage_patch(patches + (bb + pf) * ND, &lds[s][wave][0], lane);

        float sacc[NC];
        #pragma unroll
        for (int c = 0; c < NC; ++c) {
            sacc[c] = v0.x * cue[c][0].x + v0.y * cue[c][0].y
                    + v0.z * cue[c][0].z + v0.w * cue[c][0].w
                    + v1.x * cue[c][1].x + v1.y * cue[c][1].y
                    + v1.z * cue[c][1].z + v1.w * cue[c][1].w
                    + v2.x * cue[c][2].x + v2.y * cue[c][2].y
                    + v2.z * cue[c][2].z + v2.w * cue[c][2].w;
        }
        #pragma unroll
        for (int c = 0; c < NC; ++c) {
            const float t = wave_sum_lane63(sacc[c]);
            if (t > best[c]) { best[c] = t; bidx[c] = pp; }
        }
    }

    // Combine the 4 waves' bests in LDS, then one plain store per cue.
    __shared__ unsigned long long lk[NWAVE][NC];
    if (lane == 63) {  // DPP sum lives in lane 63
        #pragma unroll
        for (int c = 0; c < NC; ++c) {
            lk[wave][c] =
                ((unsigned long long)ord_of(best[c]) << 32) |
                (unsigned long long)(unsigned)(NP - 1 - bidx[c]);  // low idx wins ties
        }
    }
    __syncthreads();
    if (threadIdx.x < NC) {
        unsigned long long k = lk[0][threadIdx.x];
        k = max(k, lk[1][threadIdx.x]);
        k = max(k, lk[2][threadIdx.x]);
        k = max(k, lk[3][threadIdx.x]);
        pkeys[(b * NC + threadIdx.x) * BPB + pb] = k;
    }
}

// One block per (b, cue): reduce partial keys, clipped-window mean,
// normalize cue & roi tokens.
__global__ __launch_bounds__(256) void roi_norm_kernel(
    const float* __restrict__ cls_tok,
    const float* __restrict__ regs,
    const float* __restrict__ patches,
    const unsigned long long* __restrict__ pkeys,
    const int* __restrict__ roi_side_p,
    float* __restrict__ out)
{
    const int b   = blockIdx.x / NC;
    const int c   = blockIdx.x % NC;
    const int tid = threadIdx.x;
    const int wave = tid >> 6, lane = tid & 63;
    const int r = roi_side_p[0] >> 1;

    // All threads redundantly reduce the BPB partial keys (uniform loads).
    const unsigned long long* pk = pkeys + (b * NC + c) * BPB;
    unsigned long long key = pk[0];
    #pragma unroll
    for (int i = 1; i < BPB; ++i) key = max(key, pk[i]);

    const int idx = NP - 1 - (int)(key & 0xFFFFFFFFu);
    const int hh = idx / NW, ww = idx % NW;
    const int h0 = max(0, hh - r), h1 = min(NH - 1, hh + r);
    const int w0 = max(0, ww - r), w1 = min(NW - 1, ww + r);
    const float inv_cnt = 1.0f / (float)((h1 - h0 + 1) * (w1 - w0 + 1));

    float a0 = 0.f, a1 = 0.f, a2 = 0.f;
    for (int h = h0; h <= h1; ++h) {
        for (int w = w0; w <= w1; ++w) {
            const float* p = patches + ((size_t)b * NP + h * NW + w) * ND;
            a0 += p[tid];
            a1 += p[tid + 256];
            a2 += p[tid + 512];
        }
    }
    a0 *= inv_cnt; a1 *= inv_cnt; a2 *= inv_cnt;

    const float* cb = (c == 0) ? (cls_tok + (size_t)b * ND)
                               : (regs + ((size_t)b * NREG + (c - 1)) * ND);
    const float v0 = cb[tid], v1 = cb[tid + 256], v2 = cb[tid + 512];

    // Block-reduce two sums of squares (cue, roi).
    float sx = v0 * v0 + v1 * v1 + v2 * v2;
    float sy = a0 * a0 + a1 * a1 + a2 * a2;
    #pragma unroll
    for (int off = 32; off > 0; off >>= 1) {
        sx += __shfl_xor(sx, off, 64);
        sy += __shfl_xor(sy, off, 64);
    }
    __shared__ float red_x[4], red_y[4];
    if (lane == 0) { red_x[wave] = sx; red_y[wave] = sy; }
    __syncthreads();
    const float tot_x = red_x[0] + red_x[1] + red_x[2] + red_x[3];
    const float tot_y = red_y[0] + red_y[1] + red_y[2] + red_y[3];
    const float inv_nc = 1.0f / fmaxf(sqrtf(tot_x), 1e-12f);
    const float inv_nr = 1.0f / fmaxf(sqrtf(tot_y), 1e-12f);

    float* oc = out + ((size_t)b * 2 * NC + c) * ND;       // cue token
    float* om = out + ((size_t)b * 2 * NC + NC + c) * ND;  // roi token
    oc[tid]       = v0 * inv_nc;
    oc[tid + 256] = v1 * inv_nc;
    oc[tid + 512] = v2 * inv_nc;
    om[tid]       = a0 * inv_nr;
    om[tid + 256] = a1 * inv_nr;
    om[tid + 512] = a2 * inv_nr;
}

extern "C" void kernel_launch(void* const* d_in, const int* in_sizes, int n_in,
                              void* d_out, int out_size, void* d_ws, size_t ws_size,
                              hipStream_t stream) {
    const float* cls_tok = (const float*)d_in[0];
    const float* regs    = (const float*)d_in[1];
    const float* patches = (const float*)d_in[2];
    const int*   roi     = (const int*)d_in[3];
    float* out = (float*)d_out;
    unsigned long long* pkeys = (unsigned long long*)d_ws;

    sim_argmax_kernel<<<NB * BPB, 256, 0, stream>>>(cls_tok, regs, patches, pkeys);
    roi_norm_kernel<<<NB * NC, 256, 0, stream>>>(cls_tok, regs, patches, pkeys, roi, out);
}

// Round 9
// 53.236 us; speedup vs baseline: 1.8306x; 1.0959x over previous
//
#include <hip/hip_runtime.h>
#include <hip/hip_bf16.h>

#define NB   64
#define NREG 4
#define ND   768
#define NH   37
#define NW   37
#define NC   5                      // 1 + NREG cues
#define NP   (NH * NW)              // 1369
#define BPB  16                     // blocks per batch -> 1024 blocks = 4/CU
#define PPB  ((NP + BPB - 1) / BPB) // 86 patches per block
#define NWAVE 4
#define DEPTH 2                     // LDS slots per wave (private double buffer)

// Map float -> unsigned int preserving order (total order, -inf .. +inf)
__device__ __forceinline__ unsigned int ord_of(float f) {
    unsigned int u = __float_as_uint(f);
    return (u & 0x80000000u) ? ~u : (u | 0x80000000u);
}

// DPP-based wave64 sum: 6 full-rate VALU steps, no LDS ops, no lgkm waits.
// Result is the full 64-lane sum in LANE 63 (other lanes hold partials).
template <int CTRL>
__device__ __forceinline__ float dpp_add_step(float x) {
    int y = __builtin_amdgcn_update_dpp(0, __float_as_int(x), CTRL, 0xf, 0xf, true);
    return x + __int_as_float(y);
}
__device__ __forceinline__ float wave_sum_lane63(float x) {
    x = dpp_add_step<0x111>(x);  // row_shr:1
    x = dpp_add_step<0x112>(x);  // row_shr:2
    x = dpp_add_step<0x114>(x);  // row_shr:4
    x = dpp_add_step<0x118>(x);  // row_shr:8
    x = dpp_add_step<0x142>(x);  // row_bcast:15
    x = dpp_add_step<0x143>(x);  // row_bcast:31
    return x;                    // lane 63 = total
}

// Issue 3x global_load_lds (1 KB each) for one patch into one wave-slot.
__device__ __forceinline__ void stage_patch(const float* __restrict__ gbase,
                                            float* lslot, int lane) {
    const float* g = gbase + lane * 4;
    #pragma unroll
    for (int k = 0; k < 3; ++k) {
        __builtin_amdgcn_global_load_lds(
            (const __attribute__((address_space(1))) void*)(g + k * 256),
            (__attribute__((address_space(3))) void*)(lslot + k * 256),
            16, 0, 0);
    }
}

__global__ __launch_bounds__(256, 4) void sim_argmax_kernel(
    const float* __restrict__ cls_tok,
    const float* __restrict__ regs,
    const float* __restrict__ patches,
    unsigned long long* __restrict__ pkeys)
{
    const int b    = blockIdx.x / BPB;
    const int pb   = blockIdx.x % BPB;
    const int wave = threadIdx.x >> 6;
    const int lane = threadIdx.x & 63;

    // Per-wave private staging buffers: 2 slots x 3 KB. No barriers needed.
    __shared__ float lds[DEPTH][NWAVE][ND];   // 24 KB

    // Preload this lane's slice of all 5 cues into registers (15 float4).
    float4 cue[NC][3];
    #pragma unroll
    for (int c = 0; c < NC; ++c) {
        const float* cb = (c == 0) ? (cls_tok + (size_t)b * ND)
                                   : (regs + ((size_t)b * NREG + (c - 1)) * ND);
        #pragma unroll
        for (int k = 0; k < 3; ++k)
            cue[c][k] = *reinterpret_cast<const float4*>(cb + k * 256 + lane * 4);
    }

    float best[NC];
    int   bidx[NC];
    #pragma unroll
    for (int c = 0; c < NC; ++c) { best[c] = -3.4e38f; bidx[c] = 0; }

    const int pstart = pb * PPB;
    const int p1     = min(NP, pstart + PPB);
    const size_t bb  = (size_t)b * NP;
    const int p0     = pstart + wave;   // wave-uniform

    // Prologue: fill both slots.
    #pragma unroll
    for (int s = 0; s < DEPTH; ++s) {
        const int pp = p0 + s * NWAVE;
        if (pp < p1) stage_patch(patches + (bb + pp) * ND, &lds[s][wave][0], lane);
    }

    int it = 0;
    for (int pp = p0; pp < p1; pp += NWAVE, ++it) {
        const int s = it & 1;
        const bool more = (pp + NWAVE) < p1;  // wave-uniform

        // Counted wait: current slot's 3 loads done; next slot's 3 stay in flight.
        if (more) asm volatile("s_waitcnt vmcnt(3)" ::: "memory");
        else      asm volatile("s_waitcnt vmcnt(0)" ::: "memory");

        const float* l = &lds[s][wave][0] + lane * 4;
        const float4 v0 = *reinterpret_cast<const float4*>(l);
        const float4 v1 = *reinterpret_cast<const float4*>(l + 256);
        const float4 v2 = *reinterpret_cast<const float4*>(l + 512);

        // Ensure the ds_reads complete before re-staging overwrites the slot.
        asm volatile("s_waitcnt lgkmcnt(0)" ::: "memory");

        // Prefetch this slot <- patch pp + 8 (issues while we compute).
        const int pf = pp + DEPTH * NWAVE;
        if (pf < p1) stage_patch(patches + (bb + pf) * ND, &lds[s][wave][0], lane);

        float sacc[NC];
        #pragma unroll
        for (int c = 0; c < NC; ++c) {
            sacc[c] = v0.x * cue[c][0].x + v0.y * cue[c][0].y
                    + v0.z * cue[c][0].z + v0.w * cue[c][0].w
                    + v1.x * cue[c][1].x + v1.y * cue[c][1].y
                    + v1.z * cue[c][1].z + v1.w * cue[c][1].w
                    + v2.x * cue[c][2].x + v2.y * cue[c][2].y
                    + v2.z * cue[c][2].z + v2.w * cue[c][2].w;
        }
        #pragma unroll
        for (int c = 0; c < NC; ++c) {
            const float t = wave_sum_lane63(sacc[c]);
            if (t > best[c]) { best[c] = t; bidx[c] = pp; }
        }
    }

    // Combine the 4 waves' bests in LDS, then one plain store per cue.
    __shared__ unsigned long long lk[NWAVE][NC];
    if (lane == 63) {  // DPP sum lives in lane 63
        #pragma unroll
        for (int c = 0; c < NC; ++c) {
            lk[wave][c] =
                ((unsigned long long)ord_of(best[c]) << 32) |
                (unsigned long long)(unsigned)(NP - 1 - bidx[c]);  // low idx wins ties
        }
    }
    __syncthreads();
    if (threadIdx.x < NC) {
        unsigned long long k = lk[0][threadIdx.x];
        k = max(k, lk[1][threadIdx.x]);
        k = max(k, lk[2][threadIdx.x]);
        k = max(k, lk[3][threadIdx.x]);
        pkeys[(b * NC + threadIdx.x) * BPB + pb] = k;
    }
}

// One block (192 threads) per (b, cue): reduce partial keys, clipped-window
// mean (branchless unrolled 5x5 for r==2, full MLP), normalize both tokens.
__global__ __launch_bounds__(192) void roi_norm_kernel(
    const float* __restrict__ cls_tok,
    const float* __restrict__ regs,
    const float* __restrict__ patches,
    const unsigned long long* __restrict__ pkeys,
    const int* __restrict__ roi_side_p,
    float* __restrict__ out)
{
    const int b   = blockIdx.x / NC;
    const int c   = blockIdx.x % NC;
    const int tid = threadIdx.x;          // 0..191, tid*4 covers 768 dims
    const int wave = tid >> 6, lane = tid & 63;
    const int r = roi_side_p[0] >> 1;

    // All threads redundantly reduce the BPB partial keys (uniform loads).
    const unsigned long long* pk = pkeys + (b * NC + c) * BPB;
    unsigned long long key = pk[0];
    #pragma unroll
    for (int i = 1; i < BPB; ++i) key = max(key, pk[i]);

    const int idx = NP - 1 - (int)(key & 0xFFFFFFFFu);
    const int hh = idx / NW, ww = idx % NW;
    const int h0 = max(0, hh - r), h1 = min(NH - 1, hh + r);
    const int w0 = max(0, ww - r), w1 = min(NW - 1, ww + r);
    const float inv_cnt = 1.0f / (float)((h1 - h0 + 1) * (w1 - w0 + 1));

    const size_t bb = (size_t)b * NP;
    float4 acc = make_float4(0.f, 0.f, 0.f, 0.f);

    if (r == 2) {
        // Branchless 5x5: 25 unconditional float4 loads, mask-FMA accumulate.
        #pragma unroll
        for (int dh = -2; dh <= 2; ++dh) {
            #pragma unroll
            for (int dw = -2; dw <= 2; ++dw) {
                const int h = hh + dh, w = ww + dw;
                const bool ok = ((unsigned)h < NH) && ((unsigned)w < NW);
                const int pidx = ok ? (h * NW + w) : idx;  // safe fallback addr
                const float m = ok ? 1.0f : 0.0f;
                const float4 v = *reinterpret_cast<const float4*>(
                    patches + (bb + pidx) * ND + tid * 4);
                acc.x += v.x * m; acc.y += v.y * m;
                acc.z += v.z * m; acc.w += v.w * m;
            }
        }
    } else {
        for (int h = h0; h <= h1; ++h) {
            for (int w = w0; w <= w1; ++w) {
                const float4 v = *reinterpret_cast<const float4*>(
                    patches + (bb + h * NW + w) * ND + tid * 4);
                acc.x += v.x; acc.y += v.y; acc.z += v.z; acc.w += v.w;
            }
        }
    }
    acc.x *= inv_cnt; acc.y *= inv_cnt; acc.z *= inv_cnt; acc.w *= inv_cnt;

    const float* cb = (c == 0) ? (cls_tok + (size_t)b * ND)
                               : (regs + ((size_t)b * NREG + (c - 1)) * ND);
    const float4 v = *reinterpret_cast<const float4*>(cb + tid * 4);

    // Block-reduce two sums of squares (cue, roi) across 3 waves.
    float sx = v.x * v.x + v.y * v.y + v.z * v.z + v.w * v.w;
    float sy = acc.x * acc.x + acc.y * acc.y + acc.z * acc.z + acc.w * acc.w;
    #pragma unroll
    for (int off = 32; off > 0; off >>= 1) {
        sx += __shfl_xor(sx, off, 64);
        sy += __shfl_xor(sy, off, 64);
    }
    __shared__ float red_x[3], red_y[3];
    if (lane == 0) { red_x[wave] = sx; red_y[wave] = sy; }
    __syncthreads();
    const float tot_x = red_x[0] + red_x[1] + red_x[2];
    const float tot_y = red_y[0] + red_y[1] + red_y[2];
    const float inv_nc = 1.0f / fmaxf(sqrtf(tot_x), 1e-12f);
    const float inv_nr = 1.0f / fmaxf(sqrtf(tot_y), 1e-12f);

    float4* oc = reinterpret_cast<float4*>(out + ((size_t)b * 2 * NC + c) * ND) + tid;
    float4* om = reinterpret_cast<float4*>(out + ((size_t)b * 2 * NC + NC + c) * ND) + tid;
    *oc = make_float4(v.x * inv_nc, v.y * inv_nc, v.z * inv_nc, v.w * inv_nc);
    *om = make_float4(acc.x * inv_nr, acc.y * inv_nr, acc.z * inv_nr, acc.w * inv_nr);
}

extern "C" void kernel_launch(void* const* d_in, const int* in_sizes, int n_in,
                              void* d_out, int out_size, void* d_ws, size_t ws_size,
                              hipStream_t stream) {
    const float* cls_tok = (const float*)d_in[0];
    const float* regs    = (const float*)d_in[1];
    const float* patches = (const float*)d_in[2];
    const int*   roi     = (const int*)d_in[3];
    float* out = (float*)d_out;
    unsigned long long* pkeys = (unsigned long long*)d_ws;

    sim_argmax_kernel<<<NB * BPB, 256, 0, stream>>>(cls_tok, regs, patches, pkeys);
    roi_norm_kernel<<<NB * NC, 192, 0, stream>>>(cls_tok, regs, patches, pkeys, roi, out);
}